// Round 10
// baseline (228.161 us; speedup 1.0000x reference)
//
#include <hip/hip_runtime.h>
#include <stdint.h>

typedef unsigned short u16;
typedef __bf16 bf16;
typedef bf16 bf16x8 __attribute__((ext_vector_type(8)));
typedef float f32x4 __attribute__((ext_vector_type(4)));
typedef u16 u16x8 __attribute__((ext_vector_type(8)));
typedef u16 u16x4 __attribute__((ext_vector_type(4)));

#define T_SEQ 2048
#define NHEAD 16
#define HD    64
#define CEMB  1024
#define QS    8388608   // elems per q/k/v tensor: 4*16*2048*64
#define QSCALE 0.18033688011112042f   // 0.125 * log2(e); softmax in exp2 domain

#define BARRIER() asm volatile("s_barrier" ::: "memory")
#define WAITV(N)  asm volatile("s_waitcnt vmcnt(" #N ")" ::: "memory")

__device__ __forceinline__ u16 f2b(float f){
  bf16 h = (bf16)f;
  return __builtin_bit_cast(u16, h);
}
__device__ __forceinline__ void glds16(const void* g, const void* l){
  __builtin_amdgcn_global_load_lds(
    (__attribute__((address_space(1))) unsigned int*)(uintptr_t)g,
    (__attribute__((address_space(3))) unsigned int*)(uintptr_t)l,
    16, 0, 0);
}

// -------- fused prep: x fp32->bf16 (4096 blocks), W_attn T (768), W_proj T (256)
__global__ __launch_bounds__(256) void prep_kernel(
    const float* __restrict__ x, u16* __restrict__ xb,
    const float* __restrict__ Wa, u16* __restrict__ Wta,
    const float* __restrict__ Wp, u16* __restrict__ Wtp)
{
  __shared__ __align__(16) u16 tile[64][72];
  const int bid = blockIdx.x;
  const int tid = threadIdx.x;
  if (bid < 4096){
    const int i = (bid * 256 + tid) * 8;
    f32x4 a = *(const f32x4*)&x[i];
    f32x4 b = *(const f32x4*)&x[i + 4];
    u16x8 h;
    #pragma unroll
    for (int j = 0; j < 4; j++){ h[j] = f2b(a[j]); h[4+j] = f2b(b[j]); }
    *(u16x8*)&xb[i] = h;
    return;
  }
  const float* src; u16* dst; int K, N, bx, by;
  if (bid < 4864){ const int j = bid - 4096; src = Wa; dst = Wta; K = 1024; N = 3072; bx = j % 48; by = j / 48; }
  else           { const int j = bid - 4864; src = Wp; dst = Wtp; K = 1024; N = 1024; bx = j % 16; by = j / 16; }
  const int n0 = bx * 64, k0 = by * 64;
  #pragma unroll
  for (int it = 0; it < 4; it++){
    const int idx = it * 256 + tid;
    const int row = idx >> 4, c4 = (idx & 15) * 4;
    f32x4 v = *(const f32x4*)&src[(size_t)(k0 + row) * N + n0 + c4];
    #pragma unroll
    for (int j = 0; j < 4; j++) tile[row][c4 + j] = f2b(v[j]);
  }
  __syncthreads();
  const int r = tid >> 3, cc = (tid & 7) * 8;
  #pragma unroll
  for (int i = 0; i < 2; i++){
    const int rr = r + i * 32;
    u16x8 v;
    #pragma unroll
    for (int j = 0; j < 8; j++) v[j] = tile[cc + j][rr];
    *(u16x8*)&dst[(size_t)(n0 + rr) * K + k0 + cc] = v;
  }
}

// ---------------- QKV GEMM: 128x128 tile, BK=32, dbuf counted-vmcnt ----------
// BK=32 halves LDS to 8KB/matrix/buffer (32KB total dbuf'd) ->
// __launch_bounds__(256,4) gives 4 blocks/CU (was 2 at 17.5% occupancy).
// Same bytes through LDS, same MFMA count; only barrier rate doubles.
// Mechanism: restore the m114 inter-block latency-hiding overlap the 64KB
// dbuf lost, while KEEPING counted-vmcnt (each wave drains only its OWN
// 4 tile-c loads; tile-c+1's 4 stay in flight across the barrier).
// LDS layout (64B rows): two global rows packed per 128B line; 16B chunk at
// (grow, k8): L = grow>>1, s = (grow&1)*4 + k8, phys = s ^ (L&7).
// Conflict-free for all 8-consecutive-lane phases on read and stage sides.
#define QSTAGE32(BUF, K0) do{ \
  glds16(&A [(size_t)(m0 + ga0) * Ktot + (K0) + gk0], &As[BUF][(size_t)tid*8]); \
  glds16(&A [(size_t)(m0 + ga1) * Ktot + (K0) + gk1], &As[BUF][(size_t)(tid+256)*8]); \
  glds16(&Bt[(size_t)(n0 + ga0) * Ktot + (K0) + gk0], &Bs[BUF][(size_t)tid*8]); \
  glds16(&Bt[(size_t)(n0 + ga1) * Ktot + (K0) + gk1], &Bs[BUF][(size_t)(tid+256)*8]); \
}while(0)

__global__ __launch_bounds__(256, 4) void gemm_qkv32(
    const u16* __restrict__ A, const u16* __restrict__ Bt,
    const float* __restrict__ bias, u16* __restrict__ out, int Ktot)
{
  __shared__ __align__(16) u16 As[2][4096];    // 8KB per buffer
  __shared__ __align__(16) u16 Bs[2][4096];
  const int tid = threadIdx.x;
  const int lane = tid & 63, wave = tid >> 6;
  const int l15 = lane & 15, l4 = lane >> 4;
  const int wm = wave >> 1, wn = wave & 1;
  const int id = blockIdx.x;
  const int m0 = (id / 24) * 128, n0 = (id % 24) * 128;   // natural order
  const int NT = Ktot >> 5;                    // 32 K-steps

  // staging: phys chunk p -> (global row, k-col)
  int ga0, gk0, ga1, gk1;
  { const int p = tid;       const int L = p >> 3, s = (p & 7) ^ (L & 7);
    ga0 = 2*L + (s >> 2); gk0 = (s & 3) * 8; }
  { const int p = tid + 256; const int L = p >> 3, s = (p & 7) ^ (L & 7);
    ga1 = 2*L + (s >> 2); gk1 = (s & 3) * 8; }

  // fragment read offsets (u16 units), constant per thread:
  // rf = Wbase + frag*16 + l15; L = rf>>1; phys = ((rf&1)*4 + l4) ^ (L&7)
  int aoff[4], boff[4];
  #pragma unroll
  for (int f = 0; f < 4; f++){
    { const int rf = wm*64 + f*16 + l15;
      const int L = rf >> 1, phys = (((rf & 1) << 2) + l4) ^ (L & 7);
      aoff[f] = L*64 + phys*8; }
    { const int rf = wn*64 + f*16 + l15;
      const int L = rf >> 1, phys = (((rf & 1) << 2) + l4) ^ (L & 7);
      boff[f] = L*64 + phys*8; }
  }

  f32x4 acc[4][4] = {};

  QSTAGE32(0, 0);                              // prologue: tile 0 -> buf 0
  for (int c = 0; c < NT; c++){
    const int cur = c & 1;
    if (c + 1 < NT){
      QSTAGE32(cur ^ 1, (c + 1) * 32);         // 4 more in flight (8 total)
      WAITV(4);                                // own tile-c loads landed
    } else {
      WAITV(0);
    }
    BARRIER();                                 // => all waves' tile-c landed

    bf16x8 af[4], bfr[4];
    #pragma unroll
    for (int mt = 0; mt < 4; mt++) af[mt]  = *(const bf16x8*)&As[cur][aoff[mt]];
    #pragma unroll
    for (int nt = 0; nt < 4; nt++) bfr[nt] = *(const bf16x8*)&Bs[cur][boff[nt]];
    #pragma unroll
    for (int mt = 0; mt < 4; mt++)
      #pragma unroll
      for (int nt = 0; nt < 4; nt++)
        acc[mt][nt] = __builtin_amdgcn_mfma_f32_16x16x32_bf16(
            af[mt], bfr[nt], acc[mt][nt], 0, 0, 0);

    BARRIER();                                 // reads done before overwrite
  }

  #pragma unroll
  for (int nt = 0; nt < 4; nt++){
    const int n = n0 + wn*64 + nt*16 + l15;
    const float bias_v = bias[n];
    const int which = n >> 10;
    const int cc = n & 1023;
    const int h = cc >> 6, d = cc & 63;
    const float sc = (which == 0) ? QSCALE : 1.0f;
    if (which == 2){
      #pragma unroll
      for (int mt = 0; mt < 4; mt++){
        const int rowg = m0 + wm*64 + mt*16 + l4*4;
        const int bb = rowg >> 11, t = rowg & 2047;
        u16x4 pk;
        #pragma unroll
        for (int r = 0; r < 4; r++) pk[r] = f2b(acc[mt][nt][r] + bias_v);
        *(u16x4*)&out[(size_t)2*QS + ((size_t)(bb*NHEAD + h)*HD + d)*T_SEQ + t] = pk;
      }
    } else {
      #pragma unroll
      for (int mt = 0; mt < 4; mt++)
        #pragma unroll
        for (int r = 0; r < 4; r++){
          const int rowg = m0 + wm*64 + mt*16 + l4*4 + r;
          const int bb = rowg >> 11, t = rowg & 2047;
          out[(size_t)which*QS + ((size_t)(bb*NHEAD + h)*T_SEQ + t)*HD + d]
              = f2b((acc[mt][nt][r] + bias_v) * sc);
        }
    }
  }
}

// ---------------- GEMM (proj): BK=64 dbuf + XCD swizzle, fp32 [M,N] out -----
// (unchanged -- part of the round-6 measured -11us)
#define QSTAGE(BUF, K0) do{ \
  _Pragma("unroll") \
  for (int ii = 0; ii < 4; ii++){ \
    const int slot0 = (wave*4 + ii) * 64; \
    const int s = slot0 + lane; \
    const int row = s >> 3; \
    const int cc8 = ((s & 7) ^ (row & 7)) * 8; \
    glds16(&A [(size_t)(m0 + row) * Ktot + (K0) + cc8], &As[BUF][slot0*8]); \
    glds16(&Bt[(size_t)(n0 + row) * Ktot + (K0) + cc8], &Bs[BUF][slot0*8]); \
  } \
}while(0)

__global__ __launch_bounds__(256) void gemm_proj(
    const u16* __restrict__ A, const u16* __restrict__ Bt,
    const float* __restrict__ bias, float* __restrict__ out, int Ktot)
{
  __shared__ __align__(16) u16 As[2][128*64];
  __shared__ __align__(16) u16 Bs[2][128*64];
  const int tid = threadIdx.x;
  const int lane = tid & 63, wave = tid >> 6;
  const int l15 = lane & 15, l4 = lane >> 4;
  const int wm = wave >> 1, wn = wave & 1;
  const int id = blockIdx.x;
  const int swz = (id & 7) * 64 + (id >> 3);
  const int m0 = (swz / 8) * 128, n0 = (swz % 8) * 128;
  const int NT = Ktot >> 6;

  f32x4 acc[4][4] = {};

  QSTAGE(0, 0);
  for (int c = 0; c < NT; c++){
    const int cur = c & 1;
    if (c + 1 < NT){
      QSTAGE(cur ^ 1, (c + 1) * 64);
      WAITV(8);
    } else {
      WAITV(0);
    }
    BARRIER();

    #pragma unroll
    for (int ks = 0; ks < 2; ks++){
      bf16x8 af[4], bfr[4];
      #pragma unroll
      for (int mt = 0; mt < 4; mt++){
        const int rf = wm*64 + mt*16 + l15;
        const int slot = rf*8 + ((ks*4 + l4) ^ (rf & 7));
        af[mt] = *(const bf16x8*)&As[cur][slot*8];
      }
      #pragma unroll
      for (int nt = 0; nt < 4; nt++){
        const int rf = wn*64 + nt*16 + l15;
        const int slot = rf*8 + ((ks*4 + l4) ^ (rf & 7));
        bfr[nt] = *(const bf16x8*)&Bs[cur][slot*8];
      }
      #pragma unroll
      for (int mt = 0; mt < 4; mt++)
        #pragma unroll
        for (int nt = 0; nt < 4; nt++)
          acc[mt][nt] = __builtin_amdgcn_mfma_f32_16x16x32_bf16(
              af[mt], bfr[nt], acc[mt][nt], 0, 0, 0);
    }
    BARRIER();
  }

  #pragma unroll
  for (int nt = 0; nt < 4; nt++){
    const int n = n0 + wn*64 + nt*16 + l15;
    const float bias_v = bias[n];
    #pragma unroll
    for (int mt = 0; mt < 4; mt++)
      #pragma unroll
      for (int r = 0; r < 4; r++){
        const int rowg = m0 + wm*64 + mt*16 + l4*4 + r;
        out[(size_t)rowg*CEMB + n] = acc[mt][nt][r] + bias_v;
      }
  }
}

// ---------------- causal flash attention, S^T, no-max softmax ----------------
// Staged K/V dbuf + counted vmcnt (round-6 known-good structure).
// Pw stride 72 -> 64 with XOR swizzle (slot ^= l15&7): kills the 8-way PV
// read conflict (3.24M SQ_LDS_BANK_CONFLICT measured in round 7's variant).
// LDS: 2x(8KB K + 8KB V) + 16KB P = 48KB -> 3 blocks/CU.
__global__ __launch_bounds__(256, 3) void attn_kernel(
    const u16* __restrict__ qb, const u16* __restrict__ kb,
    const u16* __restrict__ vtb, u16* __restrict__ y)
{
  __shared__ __align__(16) u16 Ks[2*64*64];   // swizzled, double-buffered
  __shared__ __align__(16) u16 Vt[2*64*64];   // swizzled (V^T rows [d][t])
  __shared__ __align__(16) u16 Pw[8*16*64];   // per (wave,group) P[q][t], swizzled
  const int tid = threadIdx.x;
  const int lane = tid & 63, wave = tid >> 6;
  const int l15 = lane & 15, l4 = lane >> 4;
  const int qt = 15 - (blockIdx.x >> 6);      // longest-first
  const int bh = blockIdx.x & 63;
  const int q0 = qt * 128;
  const size_t base = (size_t)bh * (T_SEQ * HD);
  const u16* qp  = qb  + base;
  const u16* kp  = kb  + base;
  const u16* vtp = vtb + base;                // [hd][T]

  const int qmin0 = q0 + wave*32;
  const int qmin1 = qmin0 + 16;

  // Q as B-operand frags for both groups
  bf16x8 qf[2][2];
  #pragma unroll
  for (int g = 0; g < 2; g++){
    const int m = qmin0 + g*16 + l15;
    qf[g][0] = *(const bf16x8*)&qp[m*HD +      l4*8];
    qf[g][1] = *(const bf16x8*)&qp[m*HD + 32 + l4*8];
  }
  f32x4 o[2][4] = {};
  float l_run[2] = {0.f, 0.f};

  // staging addresses (constant per thread): 2 chunks each for K and V
  const int s0i = (wave*2 + 0) * 64 + lane;
  const int s1i = (wave*2 + 1) * 64 + lane;
  const int row0 = s0i >> 3, c0 = (s0i & 7) ^ (row0 & 7);
  const int row1 = s1i >> 3, c1 = (s1i & 7) ^ (row1 & 7);
  const int koff0 = row0*HD + c0*8, koff1 = row1*HD + c1*8;
  const int voff0 = row0*T_SEQ + c0*8, voff1 = row1*T_SEQ + c1*8;
  const int ldso0 = (wave*2 + 0) * 64 * 8, ldso1 = (wave*2 + 1) * 64 * 8;

  // Pw addressing (u16 units): row l15, 8 slots of 16B, phys slot = s^(l15&7)
  const int px7 = l15 & 7;
  const int pwb0 = (wave*2 + 0) * 1024 + l15*64;
  const int pwb1 = (wave*2 + 1) * 1024 + l15*64;

  const int nkt = 2*qt + 2;

  // prologue: stage tile 0 into buffer 0
  glds16(&kp [koff0], &Ks[ldso0]);
  glds16(&kp [koff1], &Ks[ldso1]);
  glds16(&vtp[voff0], &Vt[ldso0]);
  glds16(&vtp[voff1], &Vt[ldso1]);

  for (int kt = 0; kt < nkt; kt++){
    const int cb = (kt & 1) * 4096;           // current LDS buffer (u16 elems)
    if (kt + 1 < nkt){
      const int nb = ((kt + 1) & 1) * 4096;   // next buffer
      glds16(&kp [(kt+1)*4096 + koff0], &Ks[nb + ldso0]);
      glds16(&kp [(kt+1)*4096 + koff1], &Ks[nb + ldso1]);
      glds16(&vtp[(kt+1)*64   + voff0], &Vt[nb + ldso0]);
      glds16(&vtp[(kt+1)*64   + voff1], &Vt[nb + ldso1]);
      WAITV(4);                               // own tile-kt loads landed
    } else {
      WAITV(0);
    }
    BARRIER();                                // => every wave's kt data landed

    const int t0 = kt*64;
    if (t0 <= qmin1 + 15){                    // wave-uniform
      const bool act0 = (t0 <= qmin0 + 15);

      // S^T = K·Q^T for both groups, sharing each K fragment read
      f32x4 s0[4], s1[4];
      #pragma unroll
      for (int nb2 = 0; nb2 < 4; nb2++){
        f32x4 a0 = {}, a1 = {};
        #pragma unroll
        for (int ks = 0; ks < 2; ks++){
          const int rf = nb2*16 + l15;
          const int slot = rf*8 + ((ks*4 + l4) ^ (rf & 7));
          bf16x8 kf = *(const bf16x8*)&Ks[cb + slot*8];
          a1 = __builtin_amdgcn_mfma_f32_16x16x32_bf16(kf, qf[1][ks], a1, 0, 0, 0);
          if (act0)
            a0 = __builtin_amdgcn_mfma_f32_16x16x32_bf16(kf, qf[0][ks], a0, 0, 0, 0);
        }
        s1[nb2] = a1; s0[nb2] = a0;
      }

      // softmax (exp2 domain, no max tracking) + P write, per group
      #pragma unroll
      for (int g = 0; g < 2; g++){
        if (g == 0 && !act0) continue;
        f32x4* sf = (g == 0) ? s0 : s1;
        const int pwb = (g == 0) ? pwb0 : pwb1;
        const int qmin = (g == 0) ? qmin0 : qmin1;
        const int qg = qmin + l15;
        float lsum = 0.f;
        if (t0 + 63 > qmin){                  // diagonal-region tile: mask
          #pragma unroll
          for (int nb2 = 0; nb2 < 4; nb2++){
            u16x4 pk;
            #pragma unroll
            for (int r = 0; r < 4; r++){
              const int t = t0 + nb2*16 + l4*4 + r;
              float p = __builtin_amdgcn_exp2f(sf[nb2][r]);
              p = (t <= qg) ? p : 0.0f;
              lsum += p;
              pk[r] = f2b(p);
            }
            const int ps = (nb2*2 + (l4 >> 1)) ^ px7;
            *(u16x4*)&Pw[pwb + ps*8 + (l4 & 1)*4] = pk;
          }
        } else {
          #pragma unroll
          for (int nb2 = 0; nb2 < 4; nb2++){
            u16x4 pk;
            #pragma unroll
            for (int r = 0; r < 4; r++){
              const float p = __builtin_amdgcn_exp2f(sf[nb2][r]);
              lsum += p;
              pk[r] = f2b(p);
            }
            const int ps = (nb2*2 + (l4 >> 1)) ^ px7;
            *(u16x4*)&Pw[pwb + ps*8 + (l4 & 1)*4] = pk;
          }
        }
        l_run[g] += lsum;
      }

      // O^T += V^T·P^T, sharing each V fragment read between groups
      #pragma unroll
      for (int ks = 0; ks < 2; ks++){
        const int prs = (ks*4 + l4) ^ px7;
        bf16x8 pf1 = *(const bf16x8*)&Pw[pwb1 + prs*8];
        bf16x8 pf0;
        if (act0) pf0 = *(const bf16x8*)&Pw[pwb0 + prs*8];
        #pragma unroll
        for (int nh = 0; nh < 4; nh++){
          const int rf = nh*16 + l15;
          const int slot = rf*8 + ((ks*4 + l4) ^ (rf & 7));
          bf16x8 vf = *(const bf16x8*)&Vt[cb + slot*8];
          o[1][nh] = __builtin_amdgcn_mfma_f32_16x16x32_bf16(vf, pf1, o[1][nh], 0, 0, 0);
          if (act0)
            o[0][nh] = __builtin_amdgcn_mfma_f32_16x16x32_bf16(vf, pf0, o[0][nh], 0, 0, 0);
        }
      }
    }
    BARRIER();                                // reads done before buffer reuse
  }

  // epilogue per group: O^T[d][q]; lane q = l15; d = nh*16 + l4*4 + r
  const int b = bh >> 4, h = bh & 15;
  #pragma unroll
  for (int g = 0; g < 2; g++){
    float lr = l_run[g];
    lr += __shfl_xor(lr, 16);
    lr += __shfl_xor(lr, 32);
    const float inv_l = 1.0f / lr;
    const int t = qmin0 + g*16 + l15;
    #pragma unroll
    for (int nh = 0; nh < 4; nh++){
      u16x4 pk;
      #pragma unroll
      for (int r = 0; r < 4; r++) pk[r] = f2b(o[g][nh][r] * inv_l);
      *(u16x4*)&y[((size_t)(b*T_SEQ + t))*CEMB + h*HD + nh*16 + l4*4] = pk;
    }
  }
}

extern "C" void kernel_launch(void* const* d_in, const int* in_sizes, int n_in,
                              void* d_out, int out_size, void* d_ws, size_t ws_size,
                              hipStream_t stream) {
  const float* x      = (const float*)d_in[0];
  const float* W_attn = (const float*)d_in[1];
  const float* b_attn = (const float*)d_in[2];
  const float* W_proj = (const float*)d_in[3];
  const float* b_proj = (const float*)d_in[4];
  float* out = (float*)d_out;
  u16* ws  = (u16*)d_ws;

  u16* Wt_attn = ws;                 // 3,145,728
  u16* Wt_proj = ws + 3145728;       // 1,048,576
  u16* xb      = ws + 4194304;       // 8,388,608 (x as bf16; reused as y)
  u16* qkv     = ws + 12582912;      // 3 * QS
  u16* y       = xb;                 // xb dead after QKV GEMM

  prep_kernel<<<5120, 256, 0, stream>>>(x, xb, W_attn, Wt_attn, W_proj, Wt_proj);
  gemm_qkv32<<<1536, 256, 0, stream>>>(xb, Wt_attn, b_attn, qkv, 1024);
  attn_kernel<<<1024, 256, 0, stream>>>(qkv, qkv + QS, qkv + 2*QS, y);
  gemm_proj<<<512, 256, 0, stream>>>(y, Wt_proj, b_proj, out, 1024);
}

// Round 13
// 221.173 us; speedup vs baseline: 1.0316x; 1.0316x over previous
//
#include <hip/hip_runtime.h>
#include <stdint.h>

typedef unsigned short u16;
typedef __bf16 bf16;
typedef bf16 bf16x8 __attribute__((ext_vector_type(8)));
typedef float f32x4 __attribute__((ext_vector_type(4)));
typedef u16 u16x8 __attribute__((ext_vector_type(8)));
typedef u16 u16x4 __attribute__((ext_vector_type(4)));

#define T_SEQ 2048
#define NHEAD 16
#define HD    64
#define CEMB  1024
#define QS    8388608   // elems per q/k/v tensor: 4*16*2048*64
#define QSCALE 0.18033688011112042f   // 0.125 * log2(e); softmax in exp2 domain

#define BARRIER() asm volatile("s_barrier" ::: "memory")
#define WAITV(N)  asm volatile("s_waitcnt vmcnt(" #N ")" ::: "memory")

__device__ __forceinline__ u16 f2b(float f){
  bf16 h = (bf16)f;
  return __builtin_bit_cast(u16, h);
}
__device__ __forceinline__ void glds16(const void* g, const void* l){
  __builtin_amdgcn_global_load_lds(
    (__attribute__((address_space(1))) unsigned int*)(uintptr_t)g,
    (__attribute__((address_space(3))) unsigned int*)(uintptr_t)l,
    16, 0, 0);
}

// -------- fused prep: x fp32->bf16 (4096 blocks), W_attn T (768), W_proj T (256)
__global__ __launch_bounds__(256) void prep_kernel(
    const float* __restrict__ x, u16* __restrict__ xb,
    const float* __restrict__ Wa, u16* __restrict__ Wta,
    const float* __restrict__ Wp, u16* __restrict__ Wtp)
{
  __shared__ __align__(16) u16 tile[64][72];
  const int bid = blockIdx.x;
  const int tid = threadIdx.x;
  if (bid < 4096){
    const int i = (bid * 256 + tid) * 8;
    f32x4 a = *(const f32x4*)&x[i];
    f32x4 b = *(const f32x4*)&x[i + 4];
    u16x8 h;
    #pragma unroll
    for (int j = 0; j < 4; j++){ h[j] = f2b(a[j]); h[4+j] = f2b(b[j]); }
    *(u16x8*)&xb[i] = h;
    return;
  }
  const float* src; u16* dst; int K, N, bx, by;
  if (bid < 4864){ const int j = bid - 4096; src = Wa; dst = Wta; K = 1024; N = 3072; bx = j % 48; by = j / 48; }
  else           { const int j = bid - 4864; src = Wp; dst = Wtp; K = 1024; N = 1024; bx = j % 16; by = j / 16; }
  const int n0 = bx * 64, k0 = by * 64;
  #pragma unroll
  for (int it = 0; it < 4; it++){
    const int idx = it * 256 + tid;
    const int row = idx >> 4, c4 = (idx & 15) * 4;
    f32x4 v = *(const f32x4*)&src[(size_t)(k0 + row) * N + n0 + c4];
    #pragma unroll
    for (int j = 0; j < 4; j++) tile[row][c4 + j] = f2b(v[j]);
  }
  __syncthreads();
  const int r = tid >> 3, cc = (tid & 7) * 8;
  #pragma unroll
  for (int i = 0; i < 2; i++){
    const int rr = r + i * 32;
    u16x8 v;
    #pragma unroll
    for (int j = 0; j < 8; j++) v[j] = tile[cc + j][rr];
    *(u16x8*)&dst[(size_t)(n0 + rr) * K + k0 + cc] = v;
  }
}

// ---------------- QKV GEMM: 128x128 tile, BK=64, dbuf counted-vmcnt ----------
// Round-8 known-good (63.0-63.6us, 817 TF).  qkv plateau confirmed stable
// against deeper pipelining (r1/r2), L2 swizzles (r6), and occupancy (r10)
// -> closed.
#define QSTAGE(BUF, K0) do{ \
  _Pragma("unroll") \
  for (int ii = 0; ii < 4; ii++){ \
    const int slot0 = (wave*4 + ii) * 64; \
    const int s = slot0 + lane; \
    const int row = s >> 3; \
    const int cc8 = ((s & 7) ^ (row & 7)) * 8; \
    glds16(&A [(size_t)(m0 + row) * Ktot + (K0) + cc8], &As[BUF][slot0*8]); \
    glds16(&Bt[(size_t)(n0 + row) * Ktot + (K0) + cc8], &Bs[BUF][slot0*8]); \
  } \
}while(0)

__global__ __launch_bounds__(256) void gemm_qkv128(
    const u16* __restrict__ A, const u16* __restrict__ Bt,
    const float* __restrict__ bias, u16* __restrict__ out, int Ktot)
{
  __shared__ __align__(16) u16 As[2][128*64];
  __shared__ __align__(16) u16 Bs[2][128*64];
  const int tid = threadIdx.x;
  const int lane = tid & 63, wave = tid >> 6;
  const int l15 = lane & 15, l4 = lane >> 4;
  const int wm = wave >> 1, wn = wave & 1;
  const int id = blockIdx.x;
  const int m0 = (id / 24) * 128, n0 = (id % 24) * 128;   // natural order
  const int NT = Ktot >> 6;

  f32x4 acc[4][4] = {};

  QSTAGE(0, 0);                                // prologue: tile 0 -> buf 0
  for (int c = 0; c < NT; c++){
    const int cur = c & 1;
    if (c + 1 < NT){
      QSTAGE(cur ^ 1, (c + 1) * 64);           // 8 more in flight (16 total)
      WAITV(8);                                // own tile-c loads landed
    } else {
      WAITV(0);
    }
    BARRIER();                                 // => all waves' tile-c landed

    #pragma unroll
    for (int ks = 0; ks < 2; ks++){
      bf16x8 af[4], bfr[4];
      #pragma unroll
      for (int mt = 0; mt < 4; mt++){
        const int rf = wm*64 + mt*16 + l15;
        const int slot = rf*8 + ((ks*4 + l4) ^ (rf & 7));
        af[mt] = *(const bf16x8*)&As[cur][slot*8];
      }
      #pragma unroll
      for (int nt = 0; nt < 4; nt++){
        const int rf = wn*64 + nt*16 + l15;
        const int slot = rf*8 + ((ks*4 + l4) ^ (rf & 7));
        bfr[nt] = *(const bf16x8*)&Bs[cur][slot*8];
      }
      #pragma unroll
      for (int mt = 0; mt < 4; mt++)
        #pragma unroll
        for (int nt = 0; nt < 4; nt++)
          acc[mt][nt] = __builtin_amdgcn_mfma_f32_16x16x32_bf16(
              af[mt], bfr[nt], acc[mt][nt], 0, 0, 0);
    }
    BARRIER();                                 // reads done before overwrite
  }

  #pragma unroll
  for (int nt = 0; nt < 4; nt++){
    const int n = n0 + wn*64 + nt*16 + l15;
    const float bias_v = bias[n];
    const int which = n >> 10;
    const int cc = n & 1023;
    const int h = cc >> 6, d = cc & 63;
    const float sc = (which == 0) ? QSCALE : 1.0f;
    if (which == 2){
      #pragma unroll
      for (int mt = 0; mt < 4; mt++){
        const int rowg = m0 + wm*64 + mt*16 + l4*4;
        const int bb = rowg >> 11, t = rowg & 2047;
        u16x4 pk;
        #pragma unroll
        for (int r = 0; r < 4; r++) pk[r] = f2b(acc[mt][nt][r] + bias_v);
        *(u16x4*)&out[(size_t)2*QS + ((size_t)(bb*NHEAD + h)*HD + d)*T_SEQ + t] = pk;
      }
    } else {
      #pragma unroll
      for (int mt = 0; mt < 4; mt++)
        #pragma unroll
        for (int r = 0; r < 4; r++){
          const int rowg = m0 + wm*64 + mt*16 + l4*4 + r;
          const int bb = rowg >> 11, t = rowg & 2047;
          out[(size_t)which*QS + ((size_t)(bb*NHEAD + h)*T_SEQ + t)*HD + d]
              = f2b((acc[mt][nt][r] + bias_v) * sc);
        }
    }
  }
}

// ---------------- GEMM (proj): BK=64 dbuf + XCD swizzle, fp32 [M,N] out -----
__global__ __launch_bounds__(256) void gemm_proj(
    const u16* __restrict__ A, const u16* __restrict__ Bt,
    const float* __restrict__ bias, float* __restrict__ out, int Ktot)
{
  __shared__ __align__(16) u16 As[2][128*64];
  __shared__ __align__(16) u16 Bs[2][128*64];
  const int tid = threadIdx.x;
  const int lane = tid & 63, wave = tid >> 6;
  const int l15 = lane & 15, l4 = lane >> 4;
  const int wm = wave >> 1, wn = wave & 1;
  const int id = blockIdx.x;
  const int swz = (id & 7) * 64 + (id >> 3);
  const int m0 = (swz / 8) * 128, n0 = (swz % 8) * 128;
  const int NT = Ktot >> 6;

  f32x4 acc[4][4] = {};

  QSTAGE(0, 0);
  for (int c = 0; c < NT; c++){
    const int cur = c & 1;
    if (c + 1 < NT){
      QSTAGE(cur ^ 1, (c + 1) * 64);
      WAITV(8);
    } else {
      WAITV(0);
    }
    BARRIER();

    #pragma unroll
    for (int ks = 0; ks < 2; ks++){
      bf16x8 af[4], bfr[4];
      #pragma unroll
      for (int mt = 0; mt < 4; mt++){
        const int rf = wm*64 + mt*16 + l15;
        const int slot = rf*8 + ((ks*4 + l4) ^ (rf & 7));
        af[mt] = *(const bf16x8*)&As[cur][slot*8];
      }
      #pragma unroll
      for (int nt = 0; nt < 4; nt++){
        const int rf = wn*64 + nt*16 + l15;
        const int slot = rf*8 + ((ks*4 + l4) ^ (rf & 7));
        bfr[nt] = *(const bf16x8*)&Bs[cur][slot*8];
      }
      #pragma unroll
      for (int mt = 0; mt < 4; mt++)
        #pragma unroll
        for (int nt = 0; nt < 4; nt++)
          acc[mt][nt] = __builtin_amdgcn_mfma_f32_16x16x32_bf16(
              af[mt], bfr[nt], acc[mt][nt], 0, 0, 0);
    }
    BARRIER();
  }

  #pragma unroll
  for (int nt = 0; nt < 4; nt++){
    const int n = n0 + wn*64 + nt*16 + l15;
    const float bias_v = bias[n];
    #pragma unroll
    for (int mt = 0; mt < 4; mt++)
      #pragma unroll
      for (int r = 0; r < 4; r++){
        const int rowg = m0 + wm*64 + mt*16 + l4*4 + r;
        out[(size_t)rowg*CEMB + n] = acc[mt][nt][r] + bias_v;
      }
  }
}

// ---------------- causal flash attention, S^T, no-max softmax ----------------
// Staged K/V dbuf + counted vmcnt (round-6 structure) + Pw stride-64 XOR
// swizzle (round-10 measured: non-qkv time -8.7us).
// LDS: 2x(8KB K + 8KB V) + 16KB P = 48KB -> 3 blocks/CU.
__global__ __launch_bounds__(256, 3) void attn_kernel(
    const u16* __restrict__ qb, const u16* __restrict__ kb,
    const u16* __restrict__ vtb, u16* __restrict__ y)
{
  __shared__ __align__(16) u16 Ks[2*64*64];   // swizzled, double-buffered
  __shared__ __align__(16) u16 Vt[2*64*64];   // swizzled (V^T rows [d][t])
  __shared__ __align__(16) u16 Pw[8*16*64];   // per (wave,group) P[q][t], swizzled
  const int tid = threadIdx.x;
  const int lane = tid & 63, wave = tid >> 6;
  const int l15 = lane & 15, l4 = lane >> 4;
  const int qt = 15 - (blockIdx.x >> 6);      // longest-first
  const int bh = blockIdx.x & 63;
  const int q0 = qt * 128;
  const size_t base = (size_t)bh * (T_SEQ * HD);
  const u16* qp  = qb  + base;
  const u16* kp  = kb  + base;
  const u16* vtp = vtb + base;                // [hd][T]

  const int qmin0 = q0 + wave*32;
  const int qmin1 = qmin0 + 16;

  // Q as B-operand frags for both groups
  bf16x8 qf[2][2];
  #pragma unroll
  for (int g = 0; g < 2; g++){
    const int m = qmin0 + g*16 + l15;
    qf[g][0] = *(const bf16x8*)&qp[m*HD +      l4*8];
    qf[g][1] = *(const bf16x8*)&qp[m*HD + 32 + l4*8];
  }
  f32x4 o[2][4] = {};
  float l_run[2] = {0.f, 0.f};

  // staging addresses (constant per thread): 2 chunks each for K and V
  const int s0i = (wave*2 + 0) * 64 + lane;
  const int s1i = (wave*2 + 1) * 64 + lane;
  const int row0 = s0i >> 3, c0 = (s0i & 7) ^ (row0 & 7);
  const int row1 = s1i >> 3, c1 = (s1i & 7) ^ (row1 & 7);
  const int koff0 = row0*HD + c0*8, koff1 = row1*HD + c1*8;
  const int voff0 = row0*T_SEQ + c0*8, voff1 = row1*T_SEQ + c1*8;
  const int ldso0 = (wave*2 + 0) * 64 * 8, ldso1 = (wave*2 + 1) * 64 * 8;

  // Pw addressing (u16 units): row l15, 8 slots of 16B, phys slot = s^(l15&7)
  const int px7 = l15 & 7;
  const int pwb0 = (wave*2 + 0) * 1024 + l15*64;
  const int pwb1 = (wave*2 + 1) * 1024 + l15*64;

  const int nkt = 2*qt + 2;

  // prologue: stage tile 0 into buffer 0
  glds16(&kp [koff0], &Ks[ldso0]);
  glds16(&kp [koff1], &Ks[ldso1]);
  glds16(&vtp[voff0], &Vt[ldso0]);
  glds16(&vtp[voff1], &Vt[ldso1]);

  for (int kt = 0; kt < nkt; kt++){
    const int cb = (kt & 1) * 4096;           // current LDS buffer (u16 elems)
    if (kt + 1 < nkt){
      const int nb = ((kt + 1) & 1) * 4096;   // next buffer
      glds16(&kp [(kt+1)*4096 + koff0], &Ks[nb + ldso0]);
      glds16(&kp [(kt+1)*4096 + koff1], &Ks[nb + ldso1]);
      glds16(&vtp[(kt+1)*64   + voff0], &Vt[nb + ldso0]);
      glds16(&vtp[(kt+1)*64   + voff1], &Vt[nb + ldso1]);
      WAITV(4);                               // own tile-kt loads landed
    } else {
      WAITV(0);
    }
    BARRIER();                                // => every wave's kt data landed

    const int t0 = kt*64;
    if (t0 <= qmin1 + 15){                    // wave-uniform
      const bool act0 = (t0 <= qmin0 + 15);

      // S^T = K·Q^T for both groups, sharing each K fragment read
      f32x4 s0[4], s1[4];
      #pragma unroll
      for (int nb2 = 0; nb2 < 4; nb2++){
        f32x4 a0 = {}, a1 = {};
        #pragma unroll
        for (int ks = 0; ks < 2; ks++){
          const int rf = nb2*16 + l15;
          const int slot = rf*8 + ((ks*4 + l4) ^ (rf & 7));
          bf16x8 kf = *(const bf16x8*)&Ks[cb + slot*8];
          a1 = __builtin_amdgcn_mfma_f32_16x16x32_bf16(kf, qf[1][ks], a1, 0, 0, 0);
          if (act0)
            a0 = __builtin_amdgcn_mfma_f32_16x16x32_bf16(kf, qf[0][ks], a0, 0, 0, 0);
        }
        s1[nb2] = a1; s0[nb2] = a0;
      }

      // softmax (exp2 domain, no max tracking) + P write, per group
      #pragma unroll
      for (int g = 0; g < 2; g++){
        if (g == 0 && !act0) continue;
        f32x4* sf = (g == 0) ? s0 : s1;
        const int pwb = (g == 0) ? pwb0 : pwb1;
        const int qmin = (g == 0) ? qmin0 : qmin1;
        const int qg = qmin + l15;
        float lsum = 0.f;
        if (t0 + 63 > qmin){                  // diagonal-region tile: mask
          #pragma unroll
          for (int nb2 = 0; nb2 < 4; nb2++){
            u16x4 pk;
            #pragma unroll
            for (int r = 0; r < 4; r++){
              const int t = t0 + nb2*16 + l4*4 + r;
              float p = __builtin_amdgcn_exp2f(sf[nb2][r]);
              p = (t <= qg) ? p : 0.0f;
              lsum += p;
              pk[r] = f2b(p);
            }
            const int ps = (nb2*2 + (l4 >> 1)) ^ px7;
            *(u16x4*)&Pw[pwb + ps*8 + (l4 & 1)*4] = pk;
          }
        } else {
          #pragma unroll
          for (int nb2 = 0; nb2 < 4; nb2++){
            u16x4 pk;
            #pragma unroll
            for (int r = 0; r < 4; r++){
              const float p = __builtin_amdgcn_exp2f(sf[nb2][r]);
              lsum += p;
              pk[r] = f2b(p);
            }
            const int ps = (nb2*2 + (l4 >> 1)) ^ px7;
            *(u16x4*)&Pw[pwb + ps*8 + (l4 & 1)*4] = pk;
          }
        }
        l_run[g] += lsum;
      }

      // O^T += V^T·P^T, sharing each V fragment read between groups
      #pragma unroll
      for (int ks = 0; ks < 2; ks++){
        const int prs = (ks*4 + l4) ^ px7;
        bf16x8 pf1 = *(const bf16x8*)&Pw[pwb1 + prs*8];
        bf16x8 pf0;
        if (act0) pf0 = *(const bf16x8*)&Pw[pwb0 + prs*8];
        #pragma unroll
        for (int nh = 0; nh < 4; nh++){
          const int rf = nh*16 + l15;
          const int slot = rf*8 + ((ks*4 + l4) ^ (rf & 7));
          bf16x8 vf = *(const bf16x8*)&Vt[cb + slot*8];
          o[1][nh] = __builtin_amdgcn_mfma_f32_16x16x32_bf16(vf, pf1, o[1][nh], 0, 0, 0);
          if (act0)
            o[0][nh] = __builtin_amdgcn_mfma_f32_16x16x32_bf16(vf, pf0, o[0][nh], 0, 0, 0);
        }
      }
    }
    BARRIER();                                // reads done before buffer reuse
  }

  // epilogue per group: O^T[d][q]; lane q = l15; d = nh*16 + l4*4 + r
  const int b = bh >> 4, h = bh & 15;
  #pragma unroll
  for (int g = 0; g < 2; g++){
    float lr = l_run[g];
    lr += __shfl_xor(lr, 16);
    lr += __shfl_xor(lr, 32);
    const float inv_l = 1.0f / lr;
    const int t = qmin0 + g*16 + l15;
    #pragma unroll
    for (int nh = 0; nh < 4; nh++){
      u16x4 pk;
      #pragma unroll
      for (int r = 0; r < 4; r++) pk[r] = f2b(o[g][nh][r] * inv_l);
      *(u16x4*)&y[((size_t)(b*T_SEQ + t))*CEMB + h*HD + nh*16 + l4*4] = pk;
    }
  }
}

extern "C" void kernel_launch(void* const* d_in, const int* in_sizes, int n_in,
                              void* d_out, int out_size, void* d_ws, size_t ws_size,
                              hipStream_t stream) {
  const float* x      = (const float*)d_in[0];
  const float* W_attn = (const float*)d_in[1];
  const float* b_attn = (const float*)d_in[2];
  const float* W_proj = (const float*)d_in[3];
  const float* b_proj = (const float*)d_in[4];
  float* out = (float*)d_out;
  u16* ws  = (u16*)d_ws;

  u16* Wt_attn = ws;                 // 3,145,728
  u16* Wt_proj = ws + 3145728;       // 1,048,576
  u16* xb      = ws + 4194304;       // 8,388,608 (x as bf16; reused as y)
  u16* qkv     = ws + 12582912;      // 3 * QS
  u16* y       = xb;                 // xb dead after QKV GEMM

  prep_kernel<<<5120, 256, 0, stream>>>(x, xb, W_attn, Wt_attn, W_proj, Wt_proj);
  gemm_qkv128<<<1536, 256, 0, stream>>>(xb, Wt_attn, b_attn, qkv, 1024);
  attn_kernel<<<1024, 256, 0, stream>>>(qkv, qkv + QS, qkv + 2*QS, y);
  gemm_proj<<<512, 256, 0, stream>>>(y, Wt_proj, b_proj, out, 1024);
}